// Round 5
// baseline (231.018 us; speedup 1.0000x reference)
//
#include <hip/hip_runtime.h>

#define LATENT 128
#define HIDDEN 256
#define OUTD   128
#define TT     100
#define DECH   64
#define NMACRO 13   // RK4 macro-steps of 8 grid intervals (last = 3)

typedef _Float16 f16x8 __attribute__((ext_vector_type(8)));
typedef float    f32x4 __attribute__((ext_vector_type(4)));

#define MFMA16(a,b,c) __builtin_amdgcn_mfma_f32_16x16x32_f16((a),(b),(c),0,0,0)

__device__ __forceinline__ float tanh_fast(float x){
    float e = __expf(2.f*x);
    return 1.f - 2.f*__builtin_amdgcn_rcpf(e + 1.f);
}

__device__ __forceinline__ f16x8 lds_rd8(const _Float16* b, int sB, int row, int colE){
    int off = row*sB + colE*2; off ^= (row&7)<<4;
    return *(const f16x8*)((const char*)b + off);
}
__device__ __forceinline__ void lds_wr1(_Float16* b, int sB, int row, int colE, float v){
    int off = row*sB + colE*2; off ^= (row&7)<<4;
    *(_Float16*)((char*)b + off) = (_Float16)v;
}

// B-frag gather from row-major fp32 W[K][N]: lane holds B[k0+8*(lane>>4)+i][n]
__device__ __forceinline__ f16x8 gbl_bfrag(const float* W, int ldN, int k0, int n){
    f16x8 f;
#pragma unroll
    for(int i=0;i<8;++i) f[i] = (_Float16)W[(size_t)(k0+i)*ldN + n];
    return f;
}

__global__ __launch_bounds__(512, 2) void ode_decoder_kernel(
    const float* __restrict__ z0, const float* __restrict__ times,
    const float* __restrict__ W1, const float* __restrict__ b1,
    const float* __restrict__ W2, const float* __restrict__ b2,
    const float* __restrict__ dW1, const float* __restrict__ db1,
    const float* __restrict__ dW2, const float* __restrict__ db2,
    const float* __restrict__ dW3, const float* __restrict__ db3,
    float* __restrict__ out)
{
    __shared__ _Float16 z_lds[16*LATENT]    __attribute__((aligned(16))); // 4 KB
    __shared__ _Float16 h_lds[16*HIDDEN]    __attribute__((aligned(16))); // 8 KB
    __shared__ _Float16 epz[2][16*LATENT]   __attribute__((aligned(16))); // 8 KB Hermite z endpoints
    __shared__ _Float16 epf[2][16*LATENT]   __attribute__((aligned(16))); // 8 KB Hermite f endpoints
    __shared__ _Float16 dw1c[16*64*8]       __attribute__((aligned(16))); // 16 KB dW1 frag cache
    __shared__ _Float16 dw3c[16*64*8]       __attribute__((aligned(16))); // 16 KB dW3 frag cache
    __shared__ _Float16 h12s[8][16*DECH]    __attribute__((aligned(16))); // 16 KB per-wave scratch
    __shared__ float    tl[TT];

    const int tid  = threadIdx.x;
    const int wv   = tid >> 6;
    const int lane = tid & 63;
    const int lr   = lane & 15;
    const int lg   = lane >> 4;
    const int row0 = 4*lg;
    const int gRow0 = blockIdx.x * 16;

    if(tid < TT) tl[tid] = times[tid];

    // ---------- chain weights pinned in VGPRs ----------
    f16x8 w1f[2][4];
#pragma unroll
    for(int t=0;t<2;++t)
#pragma unroll
        for(int q=0;q<4;++q)
            w1f[t][q] = gbl_bfrag(W1, HIDDEN, 32*q+8*lg, 32*wv+16*t+lr);
    f16x8 w2f[8];
#pragma unroll
    for(int q=0;q<8;++q)
        w2f[q] = gbl_bfrag(W2, LATENT, 32*q+8*lg, 16*wv+lr);

    // ---------- decoder weights: dW2 in VGPR; dW1/dW3 in LDS frag caches ----------
    f16x8 dw2f[4][2];
#pragma unroll
    for(int n=0;n<4;++n)
#pragma unroll
        for(int q=0;q<2;++q)
            dw2f[n][q] = gbl_bfrag(dW2, DECH, 32*q+8*lg, 16*n+lr);
    {   // fill caches: 16 frags each, 2 per wave
#pragma unroll
        for(int ff=0;ff<2;++ff){
            int f = wv + 8*ff;
            int n1 = f>>2, q1 = f&3;
            *(f16x8*)(dw1c + ((size_t)f*64+lane)*8) = gbl_bfrag(dW1, DECH, 32*q1+8*lg, 16*n1+lr);
            int n3 = f>>1, q3 = f&1;
            *(f16x8*)(dw3c + ((size_t)f*64+lane)*8) = gbl_bfrag(dW3, OUTD, 32*q3+8*lg, 16*n3+lr);
        }
    }

    const float b1v0 = b1[32*wv+lr], b1v1 = b1[32*wv+16+lr];
    const float b2v  = b2[16*wv+lr];
    float db1v4[4], db2v4[4], db3v8[8];
#pragma unroll
    for(int n=0;n<4;++n){ db1v4[n] = db1[16*n+lr]; db2v4[n] = db2[16*n+lr]; }
#pragma unroll
    for(int n=0;n<8;++n) db3v8[n] = db3[16*n+lr];

    // ---------- state ----------
    f32x4 z, acc = {0,0,0,0};
#pragma unroll
    for(int r=0;r<4;++r) z[r] = z0[(size_t)(gRow0+row0+r)*LATENT + 16*wv + lr];
#pragma unroll
    for(int r=0;r<4;++r) lds_wr1(z_lds, LATENT*2, row0+r, 16*wv+lr, z[r]);
    __syncthreads();

    // ---------- chain segment bodies ----------
    auto G1SEG = [&]{
        f16x8 az[4];
#pragma unroll
        for(int q=0;q<4;++q) az[q] = lds_rd8(z_lds, LATENT*2, lr, 32*q+8*lg);
        f32x4 c0 = {b1v0,b1v0,b1v0,b1v0};
        f32x4 c1 = {b1v1,b1v1,b1v1,b1v1};
#pragma unroll
        for(int q=0;q<4;++q){ c0 = MFMA16(az[q], w1f[0][q], c0); c1 = MFMA16(az[q], w1f[1][q], c1); }
#pragma unroll
        for(int r=0;r<4;++r){
            lds_wr1(h_lds, HIDDEN*2, row0+r, 32*wv+lr,    tanh_fast(c0[r]));
            lds_wr1(h_lds, HIDDEN*2, row0+r, 32*wv+16+lr, tanh_fast(c1[r]));
        }
    };
    auto G2SEG = [&]() -> f32x4 {
        f16x8 ah[8];
#pragma unroll
        for(int q=0;q<8;++q) ah[q] = lds_rd8(h_lds, HIDDEN*2, lr, 32*q+8*lg);
        f32x4 ca = {b2v,b2v,b2v,b2v}, cb = {0,0,0,0};
#pragma unroll
        for(int q=0;q<4;++q){ ca = MFMA16(ah[q], w2f[q], ca); cb = MFMA16(ah[4+q], w2f[4+q], cb); }
        return ca + cb;
    };
    auto WRZ = [&](f32x4 zs){
#pragma unroll
        for(int r=0;r<4;++r) lds_wr1(z_lds, LATENT*2, row0+r, 16*wv+lr, zs[r]);
    };
    auto WREP = [&](int pr, f32x4 zz, f32x4 ff){
#pragma unroll
        for(int r=0;r<4;++r){
            lds_wr1(epz[pr], LATENT*2, row0+r, 16*wv+lr, zz[r]);
            lds_wr1(epf[pr], LATENT*2, row0+r, 16*wv+lr, ff[r]);
        }
    };

    // ---------- per-wave decode state + chunk bodies (wave wv decodes one grid point) ----------
    int   p = 0, par = 0, parB = 0;
    float a0=0.f, a1=0.f, a2=0.f, a3=0.f;
    f32x4 d1[4], d2[4], d3[8];

    auto DCH1 = [&](int q0, int q1){          // Hermite A-frags + partial dG1
#pragma unroll
        for(int q=q0;q<=q1;++q){
            f16x8 za = lds_rd8(epz[par],  LATENT*2, lr, 32*q+8*lg);
            f16x8 fa = lds_rd8(epf[par],  LATENT*2, lr, 32*q+8*lg);
            f16x8 zb = lds_rd8(epz[parB], LATENT*2, lr, 32*q+8*lg);
            f16x8 fb = lds_rd8(epf[parB], LATENT*2, lr, 32*q+8*lg);
            f16x8 a;
#pragma unroll
            for(int i=0;i<8;++i)
                a[i] = (_Float16)(a0*(float)za[i] + a1*(float)fa[i] + a2*(float)zb[i] + a3*(float)fb[i]);
#pragma unroll
            for(int n=0;n<4;++n)
                d1[n] = MFMA16(a, *(const f16x8*)(dw1c + ((size_t)(n*4+q)*64+lane)*8), d1[n]);
        }
    };
    auto DCH2 = [&]{                           // h1 roundtrip + dG2
#pragma unroll
        for(int n=0;n<4;++n)
#pragma unroll
            for(int r=0;r<4;++r)
                lds_wr1(h12s[wv], DECH*2, row0+r, 16*n+lr, fmaxf(d1[n][r],0.f));
#pragma unroll
        for(int n=0;n<4;++n) d2[n] = (f32x4){db2v4[n],db2v4[n],db2v4[n],db2v4[n]};
#pragma unroll
        for(int q=0;q<2;++q){
            f16x8 a = lds_rd8(h12s[wv], DECH*2, lr, 32*q+8*lg);
#pragma unroll
            for(int n=0;n<4;++n) d2[n] = MFMA16(a, dw2f[n][q], d2[n]);
        }
    };
    auto DCH3 = [&]{                           // h2 roundtrip + dG3
#pragma unroll
        for(int n=0;n<4;++n)
#pragma unroll
            for(int r=0;r<4;++r)
                lds_wr1(h12s[wv], DECH*2, row0+r, 16*n+lr, fmaxf(d2[n][r],0.f));
#pragma unroll
        for(int n=0;n<8;++n) d3[n] = (f32x4){db3v8[n],db3v8[n],db3v8[n],db3v8[n]};
#pragma unroll
        for(int q=0;q<2;++q){
            f16x8 a = lds_rd8(h12s[wv], DECH*2, lr, 32*q+8*lg);
#pragma unroll
            for(int n=0;n<8;++n)
                d3[n] = MFMA16(a, *(const f16x8*)(dw3c + ((size_t)(n*2+q)*64+lane)*8), d3[n]);
        }
    };
    auto DCH4 = [&]{                           // stores
#pragma unroll
        for(int n=0;n<8;++n)
#pragma unroll
            for(int r=0;r<4;++r)
                out[(size_t)(gRow0+row0+r)*TT*OUTD + (size_t)p*OUTD + 16*n+lr] = d3[n][r];
    };

    // ---------- main loop ----------
#pragma unroll 1
    for(int j=0;j<NMACRO;++j){
        const int  m0 = 8*j;
        const int  m1 = (m0+8 < TT-1) ? m0+8 : TT-1;
        const float hj = tl[m1]-tl[m0];
        const bool dec = (j>=1);
        if(dec){
            p = 8*(j-1)+wv;
            par = (j-1)&1; parB = j&1;
            float t0 = tl[8*(j-1)], hp = tl[8*j]-t0, rhp = 1.f/hp;
            float th = (tl[p]-t0)*rhp, t2 = th*th, t3 = t2*th;
            a0 = 2.f*t3-3.f*t2+1.f; a1 = (t3-2.f*t2+th)*hp;
            a2 = 3.f*t2-2.f*t3;     a3 = (t3-t2)*hp;
        }

        // stage 0
        G1SEG();
        __syncthreads();
        {
            f32x4 k1 = G2SEG();
            WREP(j&1, z, k1);
            acc = z + k1*(hj*(1.f/6.f));
            WRZ(z + k1*(hj*0.5f));
        }
        __syncthreads();
        // stage 1
        G1SEG();
        if(dec){
#pragma unroll
            for(int n=0;n<4;++n) d1[n] = (f32x4){db1v4[n],db1v4[n],db1v4[n],db1v4[n]};
            DCH1(0,1);
        }
        __syncthreads();
        {
            f32x4 k2 = G2SEG();
            if(dec) DCH1(2,3);
            acc += k2*(hj*(1.f/3.f));
            WRZ(z + k2*(hj*0.5f));
        }
        __syncthreads();
        // stage 2
        G1SEG();
        if(dec) DCH2();
        __syncthreads();
        {
            f32x4 k3 = G2SEG();
            if(dec) DCH3();
            acc += k3*(hj*(1.f/3.f));
            WRZ(z + k3*hj);
        }
        __syncthreads();
        // stage 3
        G1SEG();
        if(dec) DCH4();
        __syncthreads();
        {
            f32x4 k4 = G2SEG();
            z = acc + k4*(hj*(1.f/6.f));
            WRZ(z);
        }
        __syncthreads();
    }

    // ---------- tail: f(z_end), publish endpoint, decode last interval (pts 96..99) ----------
    G1SEG();
    __syncthreads();
    {
        f32x4 k1 = G2SEG();
        WREP(NMACRO&1, z, k1);
    }
    __syncthreads();
    if(wv < 4){
        p = 8*(NMACRO-1)+wv;
        par = (NMACRO-1)&1; parB = NMACRO&1;
        float t0 = tl[8*(NMACRO-1)], hp = tl[TT-1]-t0, rhp = 1.f/hp;
        float th = (tl[p]-t0)*rhp, t2 = th*th, t3 = t2*th;
        a0 = 2.f*t3-3.f*t2+1.f; a1 = (t3-2.f*t2+th)*hp;
        a2 = 3.f*t2-2.f*t3;     a3 = (t3-t2)*hp;
#pragma unroll
        for(int n=0;n<4;++n) d1[n] = (f32x4){db1v4[n],db1v4[n],db1v4[n],db1v4[n]};
        DCH1(0,3);
        DCH2();
        DCH3();
        DCH4();
    }
}

extern "C" void kernel_launch(void* const* d_in, const int* in_sizes, int n_in,
                              void* d_out, int out_size, void* d_ws, size_t ws_size,
                              hipStream_t stream) {
    ode_decoder_kernel<<<dim3(256), dim3(512), 0, stream>>>(
        (const float*)d_in[0],  (const float*)d_in[1],
        (const float*)d_in[2],  (const float*)d_in[3],
        (const float*)d_in[4],  (const float*)d_in[5],
        (const float*)d_in[6],  (const float*)d_in[7],
        (const float*)d_in[8],  (const float*)d_in[9],
        (const float*)d_in[10], (const float*)d_in[11],
        (float*)d_out);
}

// Round 6
// 128.432 us; speedup vs baseline: 1.7988x; 1.7988x over previous
//
#include <hip/hip_runtime.h>

#define LATENT 128
#define HIDDEN 256
#define OUTD   128
#define TT     100
#define DECH   64
#define NMACRO 13   // RK4 macro-steps of 8 grid intervals (last = 3)
#define WGSZ   256  // 4 waves

typedef _Float16 f16x8 __attribute__((ext_vector_type(8)));
typedef float    f32x4 __attribute__((ext_vector_type(4)));

#define MFMA16(a,b,c) __builtin_amdgcn_mfma_f32_16x16x32_f16((a),(b),(c),0,0,0)

__device__ __forceinline__ float tanh_fast(float x){
    float e = __expf(2.f*x);
    return 1.f - 2.f*__builtin_amdgcn_rcpf(e + 1.f);
}

__device__ __forceinline__ f16x8 lds_rd8(const _Float16* b, int sB, int row, int colE){
    int off = row*sB + colE*2; off ^= (row&7)<<4;
    return *(const f16x8*)((const char*)b + off);
}
__device__ __forceinline__ void lds_wr1(_Float16* b, int sB, int row, int colE, float v){
    int off = row*sB + colE*2; off ^= (row&7)<<4;
    *(_Float16*)((char*)b + off) = (_Float16)v;
}

// B-frag gather from row-major fp32 W[K][N]: lane holds B[k0+8*(lane>>4)+i][n]
__device__ __forceinline__ f16x8 gbl_bfrag(const float* W, int ldN, int k0, int n){
    f16x8 f;
#pragma unroll
    for(int i=0;i<8;++i) f[i] = (_Float16)W[(size_t)(k0+i)*ldN + n];
    return f;
}

__global__ __launch_bounds__(WGSZ, 1) void ode_decoder_kernel(
    const float* __restrict__ z0, const float* __restrict__ times,
    const float* __restrict__ W1, const float* __restrict__ b1,
    const float* __restrict__ W2, const float* __restrict__ b2,
    const float* __restrict__ dW1, const float* __restrict__ db1,
    const float* __restrict__ dW2, const float* __restrict__ db2,
    const float* __restrict__ dW3, const float* __restrict__ db3,
    float* __restrict__ out)
{
    __shared__ _Float16 z_lds[16*LATENT]  __attribute__((aligned(16))); // 4 KB
    __shared__ _Float16 h_lds[16*HIDDEN]  __attribute__((aligned(16))); // 8 KB
    __shared__ _Float16 zint [64*LATENT]  __attribute__((aligned(16))); // 16 KB (4 pts x 16 rows)
    __shared__ _Float16 h1int[64*DECH]    __attribute__((aligned(16))); // 8 KB
    __shared__ _Float16 h2int[64*DECH]    __attribute__((aligned(16))); // 8 KB
    __shared__ float    tl[TT];

    const int tid  = threadIdx.x;
    const int wv   = tid >> 6;      // 0..3
    const int lane = tid & 63;
    const int lr   = lane & 15;
    const int lg   = lane >> 4;
    const int row0 = 4*lg;
    const int gRow0 = blockIdx.x * 16;

    if(tid < TT) tl[tid] = times[tid];

    // ---------- chain weights in VGPRs ----------
    f16x8 w1f[4][4];                 // G1: wave owns N-cols [64wv, 64wv+64)
#pragma unroll
    for(int t=0;t<4;++t)
#pragma unroll
        for(int q=0;q<4;++q)
            w1f[t][q] = gbl_bfrag(W1, HIDDEN, 32*q+8*lg, 64*wv+16*t+lr);
    f16x8 w2f[2][8];                 // G2: wave owns N-cols [32wv, 32wv+32)
#pragma unroll
    for(int u=0;u<2;++u)
#pragma unroll
        for(int q=0;q<8;++q)
            w2f[u][q] = gbl_bfrag(W2, LATENT, 32*q+8*lg, 32*wv+16*u+lr);

    // ---------- decoder weights in VGPRs ----------
    f16x8 dw1B[4][4];                // dG1 m-parallel: full dW1 (all N=64)
#pragma unroll
    for(int n=0;n<4;++n)
#pragma unroll
        for(int q=0;q<4;++q)
            dw1B[n][q] = gbl_bfrag(dW1, DECH, 32*q+8*lg, 16*n+lr);
    f16x8 dw2f[2];                   // dG2 n-parallel: wave's 16-col slice
#pragma unroll
    for(int q=0;q<2;++q) dw2f[q] = gbl_bfrag(dW2, DECH, 32*q+8*lg, 16*wv+lr);
    f16x8 dw3f[2][2];                // dG3 n-parallel: wave's 32-col slice
#pragma unroll
    for(int u=0;u<2;++u)
#pragma unroll
        for(int q=0;q<2;++q)
            dw3f[u][q] = gbl_bfrag(dW3, OUTD, 32*q+8*lg, 32*wv+16*u+lr);

    float b1v[4], b2v[2], db1n[4], db3v[2];
#pragma unroll
    for(int t=0;t<4;++t) b1v[t] = b1[64*wv+16*t+lr];
#pragma unroll
    for(int u=0;u<2;++u){ b2v[u] = b2[32*wv+16*u+lr]; db3v[u] = db3[32*wv+16*u+lr]; }
#pragma unroll
    for(int n=0;n<4;++n) db1n[n] = db1[16*n+lr];
    const float db2v = db2[16*wv+lr];

    // ---------- state: lane owns z[row0+r][32wv+16u+lr] ----------
    f32x4 z[2], acc[2], zA[2] = {{0,0,0,0},{0,0,0,0}}, fA[2] = {{0,0,0,0},{0,0,0,0}}, fN[2];
#pragma unroll
    for(int u=0;u<2;++u)
#pragma unroll
        for(int r=0;r<4;++r){
            z[u][r] = z0[(size_t)(gRow0+row0+r)*LATENT + 32*wv+16*u+lr];
            lds_wr1(z_lds, LATENT*2, row0+r, 32*wv+16*u+lr, z[u][r]);
        }
    __syncthreads();

    // ---------- chain segment bodies ----------
    auto G1SEG = [&]{
        f16x8 az[4];
#pragma unroll
        for(int q=0;q<4;++q) az[q] = lds_rd8(z_lds, LATENT*2, lr, 32*q+8*lg);
        f32x4 c[4];
#pragma unroll
        for(int t=0;t<4;++t) c[t] = (f32x4){b1v[t],b1v[t],b1v[t],b1v[t]};
#pragma unroll
        for(int q=0;q<4;++q)
#pragma unroll
            for(int t=0;t<4;++t) c[t] = MFMA16(az[q], w1f[t][q], c[t]);
#pragma unroll
        for(int t=0;t<4;++t)
#pragma unroll
            for(int r=0;r<4;++r)
                lds_wr1(h_lds, HIDDEN*2, row0+r, 64*wv+16*t+lr, tanh_fast(c[t][r]));
    };
    auto G2SEG = [&](f32x4 kk[2]){
        f16x8 ah[8];
#pragma unroll
        for(int q=0;q<8;++q) ah[q] = lds_rd8(h_lds, HIDDEN*2, lr, 32*q+8*lg);
#pragma unroll
        for(int u=0;u<2;++u){
            f32x4 ca = (f32x4){b2v[u],b2v[u],b2v[u],b2v[u]};
            f32x4 cb = (f32x4){0,0,0,0};
#pragma unroll
            for(int q=0;q<4;++q){ ca = MFMA16(ah[q], w2f[u][q], ca); cb = MFMA16(ah[4+q], w2f[u][4+q], cb); }
            kk[u] = ca + cb;
        }
    };
    auto WRZ = [&](f32x4 zs0, f32x4 zs1){
#pragma unroll
        for(int r=0;r<4;++r){
            lds_wr1(z_lds, LATENT*2, row0+r, 32*wv+lr,    zs0[r]);
            lds_wr1(z_lds, LATENT*2, row0+r, 32*wv+16+lr, zs1[r]);
        }
    };
    // Hermite dense output: pts basePt..basePt+3 of interval [t0,t0+hp] -> zint
    auto INTERP4 = [&](int basePt, float t0, float hp, float rhp){
#pragma unroll
        for(int i=0;i<4;++i){
            float th = (tl[basePt+i]-t0)*rhp;
            float t2 = th*th, t3 = t2*th;
            float a0 = 2.f*t3-3.f*t2+1.f, a1 = (t3-2.f*t2+th)*hp;
            float a2 = 3.f*t2-2.f*t3,     a3 = (t3-t2)*hp;
#pragma unroll
            for(int u=0;u<2;++u)
#pragma unroll
                for(int r=0;r<4;++r){
                    float v = a0*zA[u][r] + a1*fA[u][r] + a2*z[u][r] + a3*fN[u][r];
                    lds_wr1(zint, LATENT*2, 16*i+row0+r, 32*wv+16*u+lr, v);
                }
        }
    };
    auto DG1 = [&]{   // m-parallel: wave = point (m-tile wv), all N=64
        f32x4 d1[4];
#pragma unroll
        for(int n=0;n<4;++n) d1[n] = (f32x4){db1n[n],db1n[n],db1n[n],db1n[n]};
#pragma unroll
        for(int q=0;q<4;++q){
            f16x8 a = lds_rd8(zint, LATENT*2, 16*wv+lr, 32*q+8*lg);
#pragma unroll
            for(int n=0;n<4;++n) d1[n] = MFMA16(a, dw1B[n][q], d1[n]);
        }
#pragma unroll
        for(int n=0;n<4;++n)
#pragma unroll
            for(int r=0;r<4;++r)
                lds_wr1(h1int, DECH*2, 16*wv+row0+r, 16*n+lr, fmaxf(d1[n][r],0.f));
    };
    auto DG2 = [&]{   // n-parallel: wave's 16-col slice, 4 m-tiles
#pragma unroll
        for(int mt=0;mt<4;++mt){
            f32x4 c = {db2v,db2v,db2v,db2v};
#pragma unroll
            for(int q=0;q<2;++q) c = MFMA16(lds_rd8(h1int, DECH*2, 16*mt+lr, 32*q+8*lg), dw2f[q], c);
#pragma unroll
            for(int r=0;r<4;++r) lds_wr1(h2int, DECH*2, 16*mt+row0+r, 16*wv+lr, fmaxf(c[r],0.f));
        }
    };
    auto DG3 = [&](int basePt){   // n-parallel: wave's 32-col slice, 4 m-tiles
#pragma unroll
        for(int mt=0;mt<4;++mt){
            f16x8 a[2];
#pragma unroll
            for(int q=0;q<2;++q) a[q] = lds_rd8(h2int, DECH*2, 16*mt+lr, 32*q+8*lg);
#pragma unroll
            for(int u=0;u<2;++u){
                f32x4 c = {db3v[u],db3v[u],db3v[u],db3v[u]};
#pragma unroll
                for(int q=0;q<2;++q) c = MFMA16(a[q], dw3f[u][q], c);
#pragma unroll
                for(int r=0;r<4;++r)
                    out[(size_t)(gRow0+row0+r)*TT*OUTD + (size_t)(basePt+mt)*OUTD + 32*wv+16*u+lr] = c[r];
            }
        }
    };

    // ---------- main: 13 macro RK4 steps; decode interval j-1 during step j ----------
#pragma unroll 1
    for(int j=0;j<NMACRO;++j){
        const int  m0 = 8*j;
        const int  m1 = (m0+8 < TT-1) ? m0+8 : TT-1;
        const float hj = tl[m1]-tl[m0];
        const bool dec   = (j>=1);
        const bool dec3b = (j>=2);
        const int  pA0 = 8*(j-1);
        const float t0  = dec ? tl[pA0] : 1.f;
        const float hp  = dec ? (tl[m0]-t0) : 1.f;
        const float rhp = 1.f/hp;
        f32x4 kk[2];

        // stage 0
        G1SEG(); if(dec3b) DG3(8*(j-2)+4);
        __syncthreads();
        {
            G2SEG(kk);
#pragma unroll
            for(int u=0;u<2;++u) fN[u] = kk[u];
            if(dec) INTERP4(pA0, t0, hp, rhp);
#pragma unroll
            for(int u=0;u<2;++u) acc[u] = z[u] + kk[u]*(hj*(1.f/6.f));
            WRZ(z[0] + kk[0]*(hj*0.5f), z[1] + kk[1]*(hj*0.5f));
        }
        __syncthreads();
        // stage 1
        G1SEG(); if(dec) DG1();
        __syncthreads();
        {
            G2SEG(kk); if(dec) DG2();
#pragma unroll
            for(int u=0;u<2;++u) acc[u] += kk[u]*(hj*(1.f/3.f));
            WRZ(z[0] + kk[0]*(hj*0.5f), z[1] + kk[1]*(hj*0.5f));
        }
        __syncthreads();
        // stage 2
        G1SEG(); if(dec) DG3(pA0);
        __syncthreads();
        {
            G2SEG(kk);
            if(dec) INTERP4(pA0+4, t0, hp, rhp);
#pragma unroll
            for(int u=0;u<2;++u){ acc[u] += kk[u]*(hj*(1.f/3.f)); }
            WRZ(z[0] + kk[0]*hj, z[1] + kk[1]*hj);
#pragma unroll
            for(int u=0;u<2;++u){ zA[u] = z[u]; fA[u] = fN[u]; }   // after last use of old endpoints
        }
        __syncthreads();
        // stage 3
        G1SEG(); if(dec) DG1();
        __syncthreads();
        {
            G2SEG(kk); if(dec) DG2();
#pragma unroll
            for(int u=0;u<2;++u) z[u] = acc[u] + kk[u]*(hj*(1.f/6.f));
            WRZ(z[0], z[1]);
        }
        __syncthreads();
    }

    // ---------- tail: DG3-B of interval 11; f(z_end); decode pts 96..99 ----------
    G1SEG(); DG3(8*(NMACRO-2)+4);
    __syncthreads();
    {
        f32x4 kk[2];
        G2SEG(kk);
#pragma unroll
        for(int u=0;u<2;++u) fN[u] = kk[u];
        const int basePt = 8*(NMACRO-1);
        const float t0 = tl[basePt], hp = tl[TT-1]-t0, rhp = 1.f/hp;
        INTERP4(basePt, t0, hp, rhp);
    }
    __syncthreads();
    DG1();
    __syncthreads();
    DG2();
    __syncthreads();
    DG3(8*(NMACRO-1));
}

extern "C" void kernel_launch(void* const* d_in, const int* in_sizes, int n_in,
                              void* d_out, int out_size, void* d_ws, size_t ws_size,
                              hipStream_t stream) {
    ode_decoder_kernel<<<dim3(256), dim3(WGSZ), 0, stream>>>(
        (const float*)d_in[0],  (const float*)d_in[1],
        (const float*)d_in[2],  (const float*)d_in[3],
        (const float*)d_in[4],  (const float*)d_in[5],
        (const float*)d_in[6],  (const float*)d_in[7],
        (const float*)d_in[8],  (const float*)d_in[9],
        (const float*)d_in[10], (const float*)d_in[11],
        (float*)d_out);
}